// Round 8
// baseline (754.733 us; speedup 1.0000x reference)
//
#include <hip/hip_runtime.h>
#include <hip/hip_bf16.h>

// ---------------- problem constants ----------------
#define BB 8
#define SS 2000
#define IN_CH 120
#define NPTS 10000
#define IC 512
#define CATCH 248
#define CATPAD 256
#define MROWS 16000          // B*S
#define MROWS4 64000         // B*S*DIRS
#define NSLICE 16
#define PTS_PER_SLICE 625

typedef __bf16 bf16x8 __attribute__((ext_vector_type(8)));
typedef float f32x4 __attribute__((ext_vector_type(4)));

#define DEVI __device__ __forceinline__

DEVI unsigned short f2bf(float f) {
    __hip_bfloat16 h = __float2bfloat16(f);
    return __builtin_bit_cast(unsigned short, h);
}
DEVI float bf2f(unsigned short u) {
    unsigned int x = ((unsigned int)u) << 16;
    return __builtin_bit_cast(float, x);
}
DEVI float leaky(float x) { return x > 0.f ? x : 0.1f * x; }

DEVI void gload16(const void* g, void* l) {
    __builtin_amdgcn_global_load_lds(
        (const unsigned int __attribute__((address_space(1)))*)g,
        (unsigned int __attribute__((address_space(3)))*)l, 16, 0, 0);
}

// XCD-chunked bijective swizzle (m204)
DEVI int xcd_swizzle() {
    int nwg = (int)gridDim.x;
    int orig = (int)blockIdx.x;
    int q = nwg >> 3, r = nwg & 7;
    int xcd = orig & 7, pos = orig >> 3;
    int base = xcd < r ? xcd * (q + 1) : r * (q + 1) + (xcd - r) * q;
    return base + pos;
}

// ---------------- workspace layout (bytes) ----------------
static const size_t OFF_FEATS  = 0;            // 8*128 f32
static const size_t OFF_PROJWT = 4096;         // 512*256 bf16
static const size_t OFF_RES0WT = 266240;       // 512*256 bf16
static const size_t OFF_RES1WT = 528384;       // 512*512 bf16
static const size_t OFF_LAYWT  = 1052672;      // 6*512*512 bf16
static const size_t OFF_MYIN   = 4198400;      // 16000*256 bf16
static const size_t OFF_R0     = 12390400;     // 16000*512 bf16
static const size_t OFF_R      = 28774400;     // 16000*512 bf16
static const size_t OFF_A0     = 45158400;     // 64000*512 bf16
static const size_t OFF_A1     = 110694400;    // 64000*512 bf16
// feats partials overlap A0 (consumed before proj writes A0)

// ---------------- weight convert: f32 [L][K][N] -> bf16 [L][N][Kpad] ----
__global__ void wconv_k(const float* __restrict__ src, unsigned short* __restrict__ dst,
                        int K, int Kpad, int N, int total) {
    int idx = blockIdx.x * 256 + threadIdx.x;
    if (idx >= total) return;
    int k = idx % Kpad;
    int rem = idx / Kpad;
    int n = rem % N;
    int l = rem / N;
    float v = (k < K) ? src[((size_t)l * K + k) * N + n] : 0.f;
    dst[idx] = f2bf(v);
}

// ---------------- kernel regression stage 1 ----------------
__global__ __launch_bounds__(256) void feats_part_k(
    const float* __restrict__ gxy, const float* __restrict__ goff,
    const float* __restrict__ bws, const float* __restrict__ g0,
    const float* __restrict__ sloc, float* __restrict__ partial) {
    int bq = blockIdx.x;
    int b = bq >> 1, q = bq & 1;
    float qx = sloc[b * 4 + q * 2 + 0];
    float qy = sloc[b * 4 + q * 2 + 1];
    int i0 = blockIdx.y * PTS_PER_SLICE;
    int iend = i0 + PTS_PER_SLICE;
    float swt = 0.f;
    float sf[64];
#pragma unroll
    for (int c = 0; c < 64; c++) sf[c] = 0.f;
    for (int i = i0 + threadIdx.x; i < iend; i += 256) {
        float gx = gxy[i * 2 + 0] + tanhf(goff[i * 2 + 0]) * 0.1f;
        float gy = gxy[i * 2 + 1] + tanhf(goff[i * 2 + 1]) * 0.1f;
        float bw = fminf(fmaxf(bws[i], 0.1f), 0.5f);
        float dx = qx - gx, dy = qy - gy;
        float w = expf(-(dx * dx + dy * dy) / (bw * bw));
        swt += w;
#pragma unroll
        for (int c = 0; c < 64; c++) sf[c] += w * g0[(size_t)i * 64 + c];
    }
#pragma unroll
    for (int c = 0; c < 64; c++)
        for (int o = 32; o; o >>= 1) sf[c] += __shfl_down(sf[c], o);
    for (int o = 32; o; o >>= 1) swt += __shfl_down(swt, o);
    __shared__ float red[4][65];
    int lane = threadIdx.x & 63, wv = threadIdx.x >> 6;
    if (lane == 0) {
#pragma unroll
        for (int c = 0; c < 64; c++) red[wv][c] = sf[c];
        red[wv][64] = swt;
    }
    __syncthreads();
    size_t base = (size_t)(blockIdx.y * 16 + bq) * 72;
    if (threadIdx.x < 64) {
        int c = threadIdx.x;
        partial[base + c] = red[0][c] + red[1][c] + red[2][c] + red[3][c];
        if (c == 0)
            partial[base + 64] = red[0][64] + red[1][64] + red[2][64] + red[3][64];
    }
}

__global__ __launch_bounds__(128) void feats_reduce_k(
    const float* __restrict__ partial, float* __restrict__ feats) {
    int bq = blockIdx.x;
    __shared__ float s[66];
    int t = threadIdx.x;
    if (t < 65) {
        float acc = 0.f;
        for (int sl = 0; sl < NSLICE; ++sl)
            acc += partial[(size_t)(sl * 16 + bq) * 72 + t];
        s[t] = acc;
    }
    __syncthreads();
    if (t < 64) {
        int b = bq >> 1, q = bq & 1;
        feats[b * 128 + q * 64 + t] = s[t] / s[64];
    }
}

// ---------------- build my_input bf16 [16000][256] ----------------
__global__ void build_k(const float* __restrict__ feats, const float* __restrict__ inp,
                        unsigned short* __restrict__ dst) {
    int idx = blockIdx.x * 256 + threadIdx.x;
    int c = idx & 255;
    int m = idx >> 8;
    int b = m / SS;
    float v;
    if (c < 128) v = feats[b * 128 + c];
    else if (c < CATCH) v = inp[(size_t)m * IN_CH + (c - 128)];
    else v = 0.f;
    dst[idx] = f2bf(v);
}

// ---------------- MFMA GEMM: 256x256 tile, BK=32, 3-buffer counted-vmcnt ----------------
// 512 threads, 8 waves (2M x 4N), per-wave output 128x64 (8x4 16x16 frags).
// LDS tile [4 kchunk][256 row][8 k] bf16 = 16KB/matrix; 3 bufs x (A+B) = 96KB -> 1 blk/CU.
// Conflict-free b128 reads (verified 0 conflicts R6/R7). Depth-2 prefetch: stage t+2
// before compute t; s_waitcnt vmcnt(4) leaves t+2's 4 loads in flight across barrier.
// EPI: 0=PROJ(expand x4 +ch0, leaky) 1=LAYER 2=LAYER+RES 3=LAYER_LAST
//      4=SIMPLE+leaky 5=SIMPLE   (Mrows masks the M edge for M=16000 cases)
template <int EPI>
__global__ __launch_bounds__(512) void gemm256_k(
    const unsigned short* __restrict__ A, const unsigned short* __restrict__ BT,
    unsigned short* __restrict__ out, int K, int Mrows,
    const float* __restrict__ bias, const float* __restrict__ chan,
    const unsigned short* __restrict__ resid) {
    __shared__ __align__(16) unsigned short lds[3][2][8192];  // [buf][A/B][4][256][8]
    const int tid = threadIdx.x;
    const int lane = tid & 63, wv = tid >> 6;
    const int wm = wv >> 2, wn = wv & 3;        // 2M x 4N
    const int c8 = lane >> 4;                   // k-chunk 0..3
    const int fr = lane & 15;
    const int hh = lane >> 4;

    const int swz = xcd_swizzle();
    const int bx = swz >> 1, by = swz & 1;      // N=512 -> 2 N-tiles

    // fragment LDS offsets (ushort units): chunk stride 256*8=2048
    int aoff[8], boff[4];
#pragma unroll
    for (int i = 0; i < 8; i++)
        aoff[i] = c8 * 2048 + (wm * 128 + i * 16 + fr) * 8;
#pragma unroll
    for (int j = 0; j < 4; j++)
        boff[j] = c8 * 2048 + (wn * 64 + j * 16 + fr) * 8;

    // staging: 2 rounds of 16B per thread per matrix; linear LDS dest
    // byte o = t*8192 + tid*16 -> chunk = o>>12, row = (o>>4)&255
    int ldso[2];
    size_t src[2];
    const unsigned short* Ab = A + (size_t)bx * 256 * K;
    const unsigned short* Bb = BT + (size_t)by * 256 * K;
#pragma unroll
    for (int t = 0; t < 2; t++) {
        int o = t * 8192 + tid * 16;
        int ck = o >> 12;
        int r = (o >> 4) & 255;
        ldso[t] = o >> 1;
        src[t] = (size_t)r * K + ck * 8;
    }

#define STAGE(kt, bf)                                                          \
    {                                                                          \
        const int koff = (kt) << 5;                                            \
        _Pragma("unroll") for (int t = 0; t < 2; t++)                          \
            gload16(Ab + src[t] + koff, &lds[bf][0][ldso[t]]);                 \
        _Pragma("unroll") for (int t = 0; t < 2; t++)                          \
            gload16(Bb + src[t] + koff, &lds[bf][1][ldso[t]]);                 \
    }

    f32x4 acc[8][4];
#pragma unroll
    for (int i = 0; i < 8; i++)
#pragma unroll
        for (int j = 0; j < 4; j++) acc[i][j] = (f32x4)0.f;

    const int nK = K >> 5;                      // 8 or 16
    STAGE(0, 0);
    STAGE(1, 1);
    asm volatile("s_waitcnt vmcnt(4)" ::: "memory");
    __builtin_amdgcn_s_barrier();
    __builtin_amdgcn_sched_barrier(0);

    int cur = 0;
    for (int kt = 0; kt < nK; ++kt) {
        const int nxt2 = cur + 2 >= 3 ? cur - 1 : cur + 2;
        if (kt + 2 < nK) STAGE(kt + 2, nxt2);
        bf16x8 av[8], bv[4];
#pragma unroll
        for (int i = 0; i < 8; i++) av[i] = *(const bf16x8*)&lds[cur][0][aoff[i]];
#pragma unroll
        for (int j = 0; j < 4; j++) bv[j] = *(const bf16x8*)&lds[cur][1][boff[j]];
        __builtin_amdgcn_s_setprio(1);
#pragma unroll
        for (int i = 0; i < 8; i++)
#pragma unroll
            for (int j = 0; j < 4; j++)
                acc[i][j] = __builtin_amdgcn_mfma_f32_16x16x32_bf16(av[i], bv[j], acc[i][j], 0, 0, 0);
        __builtin_amdgcn_s_setprio(0);
        if (kt + 1 < nK) {
            if (kt + 2 < nK) {
                asm volatile("s_waitcnt vmcnt(4)" ::: "memory");  // t+1 done, t+2 flying
            } else {
                asm volatile("s_waitcnt vmcnt(0)" ::: "memory");  // tail
            }
            __builtin_amdgcn_s_barrier();
            __builtin_amdgcn_sched_barrier(0);
        }
        cur = cur + 1 >= 3 ? 0 : cur + 1;
    }
#undef STAGE

    // epilogue: C/D frag: col = lane&15, row = (lane>>4)*4 + reg   [m89-verified]
    const size_t m0 = (size_t)bx * 256 + wm * 128;
    const int n0 = by * 256 + wn * 64;
#pragma unroll
    for (int i = 0; i < 8; i++) {
#pragma unroll
        for (int j = 0; j < 4; j++) {
#pragma unroll
            for (int rg = 0; rg < 4; ++rg) {
                size_t m = m0 + i * 16 + hh * 4 + rg;
                int n = n0 + j * 16 + fr;
                if (m >= (size_t)Mrows) continue;
                float v = acc[i][j][rg];
                if constexpr (EPI == 0) {
                    float v0 = v + bias[n];
#pragma unroll
                    for (int d = 0; d < 4; ++d) {
                        float u = v0 + chan[d * 512 + n];
                        out[(m * 4 + d) * 512 + n] = f2bf(leaky(u));
                    }
                } else if constexpr (EPI == 1 || EPI == 2 || EPI == 3) {
                    int d = (int)(m & 3);
                    float u = v + bias[n] + chan[d * 512 + n];
                    if constexpr (EPI == 2) u += bf2f(resid[(m >> 2) * 512 + n]);
                    out[m * 512 + n] = f2bf(EPI == 3 ? u : leaky(u));
                } else {
                    float u = v + bias[n];
                    out[m * 512 + n] = f2bf(EPI == 4 ? leaky(u) : u);
                }
            }
        }
    }
}

// ---------------- final: out[64000][2] ----------------
__global__ __launch_bounds__(256) void final_k(
    const unsigned short* __restrict__ A, const float* __restrict__ outW,
    const float* __restrict__ outb, float* __restrict__ out) {
    int gw = blockIdx.x * 4 + (threadIdx.x >> 6);
    int lane = threadIdx.x & 63;
    const unsigned short* row = A + (size_t)gw * 512;
    uint4 bits = *(const uint4*)(row + lane * 8);
    unsigned int ww[4] = {bits.x, bits.y, bits.z, bits.w};
    float s0 = 0.f, s1 = 0.f;
#pragma unroll
    for (int j = 0; j < 8; j++) {
        unsigned short u = (unsigned short)((ww[j >> 1] >> ((j & 1) * 16)) & 0xffff);
        float a = bf2f(u);
        int k = lane * 8 + j;
        s0 = fmaf(a, outW[k * 2 + 0], s0);
        s1 = fmaf(a, outW[k * 2 + 1], s1);
    }
    for (int o = 32; o; o >>= 1) {
        s0 += __shfl_down(s0, o);
        s1 += __shfl_down(s1, o);
    }
    if (lane == 0) {
        out[(size_t)gw * 2 + 0] = s0 + outb[0];
        out[(size_t)gw * 2 + 1] = s1 + outb[1];
    }
}

extern "C" void kernel_launch(void* const* d_in, const int* in_sizes, int n_in,
                              void* d_out, int out_size, void* d_ws, size_t ws_size,
                              hipStream_t stream) {
    const float* input_stuff = (const float*)d_in[0];
    const float* sound_loc   = (const float*)d_in[1];
    const float* grid_xy     = (const float*)d_in[2];
    const float* xy_offset   = (const float*)d_in[3];
    const float* bandwidths  = (const float*)d_in[4];
    const float* grid_0      = (const float*)d_in[5];
    const float* proj_W      = (const float*)d_in[6];
    const float* proj_b      = (const float*)d_in[7];
    const float* res_W0      = (const float*)d_in[8];
    const float* res_b0      = (const float*)d_in[9];
    const float* res_W1      = (const float*)d_in[10];
    const float* res_b1      = (const float*)d_in[11];
    const float* layers_W    = (const float*)d_in[12];
    const float* layers_b    = (const float*)d_in[13];
    const float* channels    = (const float*)d_in[14];
    const float* out_W       = (const float*)d_in[15];
    const float* out_b       = (const float*)d_in[16];

    char* ws = (char*)d_ws;
    float* feats            = (float*)(ws + OFF_FEATS);
    unsigned short* projWT  = (unsigned short*)(ws + OFF_PROJWT);
    unsigned short* res0WT  = (unsigned short*)(ws + OFF_RES0WT);
    unsigned short* res1WT  = (unsigned short*)(ws + OFF_RES1WT);
    unsigned short* layWT   = (unsigned short*)(ws + OFF_LAYWT);
    unsigned short* myin    = (unsigned short*)(ws + OFF_MYIN);
    unsigned short* R0      = (unsigned short*)(ws + OFF_R0);
    unsigned short* Rb      = (unsigned short*)(ws + OFF_R);
    unsigned short* A0      = (unsigned short*)(ws + OFF_A0);
    unsigned short* A1      = (unsigned short*)(ws + OFF_A1);
    float* partial          = (float*)(ws + OFF_A0);

    wconv_k<<<(512 * 256 + 255) / 256, 256, 0, stream>>>(proj_W, projWT, CATCH, CATPAD, IC, 512 * 256);
    wconv_k<<<(512 * 256 + 255) / 256, 256, 0, stream>>>(res_W0, res0WT, CATCH, CATPAD, IC, 512 * 256);
    wconv_k<<<(512 * 512 + 255) / 256, 256, 0, stream>>>(res_W1, res1WT, IC, IC, IC, 512 * 512);
    wconv_k<<<(6 * 512 * 512 + 255) / 256, 256, 0, stream>>>(layers_W, layWT, IC, IC, IC, 6 * 512 * 512);

    feats_part_k<<<dim3(16, NSLICE), 256, 0, stream>>>(grid_xy, xy_offset, bandwidths, grid_0, sound_loc, partial);
    feats_reduce_k<<<16, 128, 0, stream>>>(partial, feats);
    build_k<<<MROWS, 256, 0, stream>>>(feats, input_stuff, myin);

    // grids: M=16000 -> 63 M-tiles x 2 N = 126; M=64000 -> 250 x 2 = 500
    // proj (+channels[0], leaky, expand x4) -> A0
    gemm256_k<0><<<126, 512, 0, stream>>>(myin, projWT, A0, CATPAD, MROWS, proj_b, channels, nullptr);
    // residual branch
    gemm256_k<4><<<126, 512, 0, stream>>>(myin, res0WT, R0, CATPAD, MROWS, res_b0, nullptr, nullptr);
    gemm256_k<5><<<126, 512, 0, stream>>>(R0, res1WT, Rb, IC, MROWS, res_b1, nullptr, nullptr);
    // 6 layers, ping-pong A0/A1; residual at k==2; k==5 last (no leaky)
    gemm256_k<1><<<500, 512, 0, stream>>>(A0, layWT + 0 * 262144, A1, IC, MROWS4, layers_b + 0 * 512, channels + 1 * 2048, nullptr);
    gemm256_k<1><<<500, 512, 0, stream>>>(A1, layWT + 1 * 262144, A0, IC, MROWS4, layers_b + 1 * 512, channels + 2 * 2048, nullptr);
    gemm256_k<2><<<500, 512, 0, stream>>>(A0, layWT + 2 * 262144, A1, IC, MROWS4, layers_b + 2 * 512, channels + 3 * 2048, Rb);
    gemm256_k<1><<<500, 512, 0, stream>>>(A1, layWT + 3 * 262144, A0, IC, MROWS4, layers_b + 3 * 512, channels + 4 * 2048, nullptr);
    gemm256_k<1><<<500, 512, 0, stream>>>(A0, layWT + 4 * 262144, A1, IC, MROWS4, layers_b + 4 * 512, channels + 5 * 2048, nullptr);
    gemm256_k<3><<<500, 512, 0, stream>>>(A1, layWT + 5 * 262144, A0, IC, MROWS4, layers_b + 5 * 512, channels + 6 * 2048, nullptr);

    final_k<<<MROWS, 256, 0, stream>>>(A0, out_W, out_b, (float*)d_out);
}

// Round 9
// 463.381 us; speedup vs baseline: 1.6288x; 1.6288x over previous
//
#include <hip/hip_runtime.h>
#include <hip/hip_bf16.h>

// ---------------- problem constants ----------------
#define BB 8
#define SS 2000
#define IN_CH 120
#define NPTS 10000
#define IC 512
#define CATCH 248
#define CATPAD 256
#define MROWS 16000          // B*S
#define MROWS4 64000         // B*S*DIRS
#define NSLICE 16
#define PTS_PER_SLICE 625

typedef __bf16 bf16x8 __attribute__((ext_vector_type(8)));
typedef float f32x4 __attribute__((ext_vector_type(4)));

#define DEVI __device__ __forceinline__

DEVI unsigned short f2bf(float f) {
    __hip_bfloat16 h = __float2bfloat16(f);
    return __builtin_bit_cast(unsigned short, h);
}
DEVI float bf2f(unsigned short u) {
    unsigned int x = ((unsigned int)u) << 16;
    return __builtin_bit_cast(float, x);
}
DEVI float leaky(float x) { return x > 0.f ? x : 0.1f * x; }

DEVI void gload16(const void* g, void* l) {
    __builtin_amdgcn_global_load_lds(
        (const unsigned int __attribute__((address_space(1)))*)g,
        (unsigned int __attribute__((address_space(3)))*)l, 16, 0, 0);
}

// ---------------- workspace layout (bytes) ----------------
static const size_t OFF_FEATS  = 0;            // 8*128 f32
static const size_t OFF_PROJWT = 4096;         // 512*256 bf16
static const size_t OFF_RES0WT = 266240;       // 512*256 bf16
static const size_t OFF_RES1WT = 528384;       // 512*512 bf16
static const size_t OFF_LAYWT  = 1052672;      // 6*512*512 bf16
static const size_t OFF_MYIN   = 4198400;      // 16000*256 bf16
static const size_t OFF_R0     = 12390400;     // 16000*512 bf16
static const size_t OFF_R      = 28774400;     // 16000*512 bf16
static const size_t OFF_A0     = 45158400;     // 64000*512 bf16
static const size_t OFF_A1     = 110694400;    // 64000*512 bf16
// feats partials overlap A0 (consumed before proj writes A0)

// ---------------- weight convert: f32 [L][K][N] -> bf16 [L][N][Kpad] ----
__global__ void wconv_k(const float* __restrict__ src, unsigned short* __restrict__ dst,
                        int K, int Kpad, int N, int total) {
    int idx = blockIdx.x * 256 + threadIdx.x;
    if (idx >= total) return;
    int k = idx % Kpad;
    int rem = idx / Kpad;
    int n = rem % N;
    int l = rem / N;
    float v = (k < K) ? src[((size_t)l * K + k) * N + n] : 0.f;
    dst[idx] = f2bf(v);
}

// ---------------- kernel regression stage 1 ----------------
__global__ __launch_bounds__(256) void feats_part_k(
    const float* __restrict__ gxy, const float* __restrict__ goff,
    const float* __restrict__ bws, const float* __restrict__ g0,
    const float* __restrict__ sloc, float* __restrict__ partial) {
    int bq = blockIdx.x;
    int b = bq >> 1, q = bq & 1;
    float qx = sloc[b * 4 + q * 2 + 0];
    float qy = sloc[b * 4 + q * 2 + 1];
    int i0 = blockIdx.y * PTS_PER_SLICE;
    int iend = i0 + PTS_PER_SLICE;
    float swt = 0.f;
    float sf[64];
#pragma unroll
    for (int c = 0; c < 64; c++) sf[c] = 0.f;
    for (int i = i0 + threadIdx.x; i < iend; i += 256) {
        float gx = gxy[i * 2 + 0] + tanhf(goff[i * 2 + 0]) * 0.1f;
        float gy = gxy[i * 2 + 1] + tanhf(goff[i * 2 + 1]) * 0.1f;
        float bw = fminf(fmaxf(bws[i], 0.1f), 0.5f);
        float dx = qx - gx, dy = qy - gy;
        float w = expf(-(dx * dx + dy * dy) / (bw * bw));
        swt += w;
#pragma unroll
        for (int c = 0; c < 64; c++) sf[c] += w * g0[(size_t)i * 64 + c];
    }
#pragma unroll
    for (int c = 0; c < 64; c++)
        for (int o = 32; o; o >>= 1) sf[c] += __shfl_down(sf[c], o);
    for (int o = 32; o; o >>= 1) swt += __shfl_down(swt, o);
    __shared__ float red[4][65];
    int lane = threadIdx.x & 63, wv = threadIdx.x >> 6;
    if (lane == 0) {
#pragma unroll
        for (int c = 0; c < 64; c++) red[wv][c] = sf[c];
        red[wv][64] = swt;
    }
    __syncthreads();
    size_t base = (size_t)(blockIdx.y * 16 + bq) * 72;
    if (threadIdx.x < 64) {
        int c = threadIdx.x;
        partial[base + c] = red[0][c] + red[1][c] + red[2][c] + red[3][c];
        if (c == 0)
            partial[base + 64] = red[0][64] + red[1][64] + red[2][64] + red[3][64];
    }
}

__global__ __launch_bounds__(128) void feats_reduce_k(
    const float* __restrict__ partial, float* __restrict__ feats) {
    int bq = blockIdx.x;
    __shared__ float s[66];
    int t = threadIdx.x;
    if (t < 65) {
        float acc = 0.f;
        for (int sl = 0; sl < NSLICE; ++sl)
            acc += partial[(size_t)(sl * 16 + bq) * 72 + t];
        s[t] = acc;
    }
    __syncthreads();
    if (t < 64) {
        int b = bq >> 1, q = bq & 1;
        feats[b * 128 + q * 64 + t] = s[t] / s[64];
    }
}

// ---------------- build my_input bf16 [16000][256] ----------------
__global__ void build_k(const float* __restrict__ feats, const float* __restrict__ inp,
                        unsigned short* __restrict__ dst) {
    int idx = blockIdx.x * 256 + threadIdx.x;
    int c = idx & 255;
    int m = idx >> 8;
    int b = m / SS;
    float v;
    if (c < 128) v = feats[b * 128 + c];
    else if (c < CATCH) v = inp[(size_t)m * IN_CH + (c - 128)];
    else v = 0.f;
    dst[idx] = f2bf(v);
}

// ---------------- persistent weights-stationary GEMM ----------------
// 256 blocks (1/CU), 512 threads (8 waves, 2M x 4N; wave = 64 rows x 32 cols).
// Block owns N-strip of 128 cols: W strip staged ONCE to LDS ([KK/8 ck][128 col][8 k],
// 2-way-max banks). A streams via 3-buffer BK=32 pipeline ([4 ck][128 row][8 k],
// counted vmcnt(1), stage t+2 while computing t). Jobs = M-tiles of the block's
// M-slice; bid&7 = XCD so 4 strips of an M-slice share A-tiles in one XCD-L2.
// EPI: 0=PROJ(expand x4 +ch0, leaky) 1=LAYER 2=LAYER+RES 3=LAYER_LAST
//      4=SIMPLE+leaky 5=SIMPLE
template <int EPI, int KK>
__global__ __launch_bounds__(512) void pers_k(
    const unsigned short* __restrict__ A, const unsigned short* __restrict__ WT,
    unsigned short* __restrict__ out, int Mtiles,
    const float* __restrict__ bias, const float* __restrict__ chan,
    const unsigned short* __restrict__ resid) {
    extern __shared__ __align__(16) unsigned short smem[];
    unsigned short* smemW = smem;                  // 128*KK ushorts
    unsigned short* smemA = smem + 128 * KK;       // 3 * 4096 ushorts
    const int tid = threadIdx.x;
    const int lane = tid & 63, wv = tid >> 6;
    const int wm = wv >> 2, wn = wv & 3;           // 2M x 4N
    const int fr = lane & 15, c8 = lane >> 4;
    const int hh = c8;

    const int bid = blockIdx.x;
    const int xcd = bid & 7, sub = bid >> 3;
    const int strip = sub & 3;
    const int msl = xcd * 8 + (sub >> 2);          // 0..63
    const int q = Mtiles >> 6, r = Mtiles & 63;
    const int start = msl < r ? msl * (q + 1) : r * (q + 1) + (msl - r) * q;
    const int count = msl < r ? q + 1 : q;

    constexpr int NK = KK / 32;

    // ---- stage W strip (once) ----
    {
        const unsigned short* Wb = WT + (size_t)(strip * 128) * KK;
        constexpr int WCH = 128 * KK / 8;          // 16B chunks
#pragma unroll
        for (int c0 = 0; c0 < WCH; c0 += 512) {
            int c = c0 + tid;
            int ck = c >> 7, col = c & 127;
            gload16(Wb + (size_t)col * KK + ck * 8, &smemW[c * 8]);
        }
    }
    asm volatile("s_waitcnt vmcnt(0)" ::: "memory");
    __builtin_amdgcn_s_barrier();
    __builtin_amdgcn_sched_barrier(0);

    const int arow = tid & 127;                    // staging decomposition
    const int ack = tid >> 7;

    for (int t = 0; t < count; ++t) {
        const int mtile = start + t;
        const unsigned short* Ab =
            A + (size_t)mtile * 128 * KK + (size_t)arow * KK + ack * 8;

        f32x4 acc[4][2];
#pragma unroll
        for (int i = 0; i < 4; i++) {
            acc[i][0] = (f32x4)0.f;
            acc[i][1] = (f32x4)0.f;
        }

        __builtin_amdgcn_s_barrier();              // A-buf reuse safety
        gload16(Ab + 0, &smemA[0 * 4096 + tid * 8]);
        gload16(Ab + 32, &smemA[1 * 4096 + tid * 8]);
        asm volatile("s_waitcnt vmcnt(1)" ::: "memory");
        __builtin_amdgcn_s_barrier();
        __builtin_amdgcn_sched_barrier(0);

#pragma unroll
        for (int kt = 0; kt < NK; ++kt) {
            if (kt + 2 < NK)
                gload16(Ab + (kt + 2) * 32, &smemA[((kt + 2) % 3) * 4096 + tid * 8]);
            const unsigned short* bufA = &smemA[(kt % 3) * 4096];
            bf16x8 av[4], bv[2];
#pragma unroll
            for (int i = 0; i < 4; i++)
                av[i] = *(const bf16x8*)&bufA[c8 * 1024 + (wm * 64 + i * 16 + fr) * 8];
#pragma unroll
            for (int j = 0; j < 2; j++)
                bv[j] = *(const bf16x8*)&smemW[(kt * 4 + c8) * 1024 + (wn * 32 + j * 16 + fr) * 8];
            __builtin_amdgcn_s_setprio(1);
#pragma unroll
            for (int i = 0; i < 4; i++)
#pragma unroll
                for (int j = 0; j < 2; j++)
                    acc[i][j] = __builtin_amdgcn_mfma_f32_16x16x32_bf16(
                        av[i], bv[j], acc[i][j], 0, 0, 0);
            __builtin_amdgcn_s_setprio(0);
            if (kt + 1 < NK) {
                if (kt + 2 < NK) {
                    asm volatile("s_waitcnt vmcnt(1)" ::: "memory");
                } else {
                    asm volatile("s_waitcnt vmcnt(0)" ::: "memory");
                }
                __builtin_amdgcn_s_barrier();
                __builtin_amdgcn_sched_barrier(0);
            }
        }

        // epilogue: C/D frag: col = lane&15, row = (lane>>4)*4 + reg  [m89-verified]
        const size_t m0 = (size_t)mtile * 128 + wm * 64;
        const int n0 = strip * 128 + wn * 32;
#pragma unroll
        for (int i = 0; i < 4; i++) {
#pragma unroll
            for (int j = 0; j < 2; j++) {
#pragma unroll
                for (int rg = 0; rg < 4; ++rg) {
                    size_t m = m0 + i * 16 + hh * 4 + rg;
                    int n = n0 + j * 16 + fr;
                    float v = acc[i][j][rg];
                    if constexpr (EPI == 0) {
                        float v0 = v + bias[n];
#pragma unroll
                        for (int d = 0; d < 4; ++d) {
                            float u = v0 + chan[d * 512 + n];
                            out[(m * 4 + d) * 512 + n] = f2bf(leaky(u));
                        }
                    } else if constexpr (EPI == 1 || EPI == 2 || EPI == 3) {
                        int d = (int)(m & 3);
                        float u = v + bias[n] + chan[d * 512 + n];
                        if constexpr (EPI == 2) u += bf2f(resid[(m >> 2) * 512 + n]);
                        out[m * 512 + n] = f2bf(EPI == 3 ? u : leaky(u));
                    } else {
                        float u = v + bias[n];
                        out[m * 512 + n] = f2bf(EPI == 4 ? leaky(u) : u);
                    }
                }
            }
        }
    }
}

// ---------------- final: out[64000][2] ----------------
__global__ __launch_bounds__(256) void final_k(
    const unsigned short* __restrict__ A, const float* __restrict__ outW,
    const float* __restrict__ outb, float* __restrict__ out) {
    int gw = blockIdx.x * 4 + (threadIdx.x >> 6);
    int lane = threadIdx.x & 63;
    const unsigned short* row = A + (size_t)gw * 512;
    uint4 bits = *(const uint4*)(row + lane * 8);
    unsigned int ww[4] = {bits.x, bits.y, bits.z, bits.w};
    float s0 = 0.f, s1 = 0.f;
#pragma unroll
    for (int j = 0; j < 8; j++) {
        unsigned short u = (unsigned short)((ww[j >> 1] >> ((j & 1) * 16)) & 0xffff);
        float a = bf2f(u);
        int k = lane * 8 + j;
        s0 = fmaf(a, outW[k * 2 + 0], s0);
        s1 = fmaf(a, outW[k * 2 + 1], s1);
    }
    for (int o = 32; o; o >>= 1) {
        s0 += __shfl_down(s0, o);
        s1 += __shfl_down(s1, o);
    }
    if (lane == 0) {
        out[(size_t)gw * 2 + 0] = s0 + outb[0];
        out[(size_t)gw * 2 + 1] = s1 + outb[1];
    }
}

extern "C" void kernel_launch(void* const* d_in, const int* in_sizes, int n_in,
                              void* d_out, int out_size, void* d_ws, size_t ws_size,
                              hipStream_t stream) {
    const float* input_stuff = (const float*)d_in[0];
    const float* sound_loc   = (const float*)d_in[1];
    const float* grid_xy     = (const float*)d_in[2];
    const float* xy_offset   = (const float*)d_in[3];
    const float* bandwidths  = (const float*)d_in[4];
    const float* grid_0      = (const float*)d_in[5];
    const float* proj_W      = (const float*)d_in[6];
    const float* proj_b      = (const float*)d_in[7];
    const float* res_W0      = (const float*)d_in[8];
    const float* res_b0      = (const float*)d_in[9];
    const float* res_W1      = (const float*)d_in[10];
    const float* res_b1      = (const float*)d_in[11];
    const float* layers_W    = (const float*)d_in[12];
    const float* layers_b    = (const float*)d_in[13];
    const float* channels    = (const float*)d_in[14];
    const float* out_W       = (const float*)d_in[15];
    const float* out_b       = (const float*)d_in[16];

    char* ws = (char*)d_ws;
    float* feats            = (float*)(ws + OFF_FEATS);
    unsigned short* projWT  = (unsigned short*)(ws + OFF_PROJWT);
    unsigned short* res0WT  = (unsigned short*)(ws + OFF_RES0WT);
    unsigned short* res1WT  = (unsigned short*)(ws + OFF_RES1WT);
    unsigned short* layWT   = (unsigned short*)(ws + OFF_LAYWT);
    unsigned short* myin    = (unsigned short*)(ws + OFF_MYIN);
    unsigned short* R0      = (unsigned short*)(ws + OFF_R0);
    unsigned short* Rb      = (unsigned short*)(ws + OFF_R);
    unsigned short* A0      = (unsigned short*)(ws + OFF_A0);
    unsigned short* A1      = (unsigned short*)(ws + OFF_A1);
    float* partial          = (float*)(ws + OFF_A0);

    static int smem_set = 0;
    if (!smem_set) {
        hipFuncSetAttribute((const void*)pers_k<0, 256>, hipFuncAttributeMaxDynamicSharedMemorySize, 90112);
        hipFuncSetAttribute((const void*)pers_k<4, 256>, hipFuncAttributeMaxDynamicSharedMemorySize, 90112);
        hipFuncSetAttribute((const void*)pers_k<5, 512>, hipFuncAttributeMaxDynamicSharedMemorySize, 155648);
        hipFuncSetAttribute((const void*)pers_k<1, 512>, hipFuncAttributeMaxDynamicSharedMemorySize, 155648);
        hipFuncSetAttribute((const void*)pers_k<2, 512>, hipFuncAttributeMaxDynamicSharedMemorySize, 155648);
        hipFuncSetAttribute((const void*)pers_k<3, 512>, hipFuncAttributeMaxDynamicSharedMemorySize, 155648);
        smem_set = 1;
    }

    wconv_k<<<(512 * 256 + 255) / 256, 256, 0, stream>>>(proj_W, projWT, CATCH, CATPAD, IC, 512 * 256);
    wconv_k<<<(512 * 256 + 255) / 256, 256, 0, stream>>>(res_W0, res0WT, CATCH, CATPAD, IC, 512 * 256);
    wconv_k<<<(512 * 512 + 255) / 256, 256, 0, stream>>>(res_W1, res1WT, IC, IC, IC, 512 * 512);
    wconv_k<<<(6 * 512 * 512 + 255) / 256, 256, 0, stream>>>(layers_W, layWT, IC, IC, IC, 6 * 512 * 512);

    feats_part_k<<<dim3(16, NSLICE), 256, 0, stream>>>(grid_xy, xy_offset, bandwidths, grid_0, sound_loc, partial);
    feats_reduce_k<<<16, 128, 0, stream>>>(partial, feats);
    build_k<<<MROWS, 256, 0, stream>>>(feats, input_stuff, myin);

    // proj (+channels[0], leaky, expand x4) -> A0          M=16000 -> 125 tiles
    pers_k<0, 256><<<256, 512, 90112, stream>>>(myin, projWT, A0, 125, proj_b, channels, nullptr);
    // residual branch
    pers_k<4, 256><<<256, 512, 90112, stream>>>(myin, res0WT, R0, 125, res_b0, nullptr, nullptr);
    pers_k<5, 512><<<256, 512, 155648, stream>>>(R0, res1WT, Rb, 125, res_b1, nullptr, nullptr);
    // 6 layers, ping-pong A0/A1; residual at k==2; k==5 last (no leaky)  M=64000 -> 500 tiles
    pers_k<1, 512><<<256, 512, 155648, stream>>>(A0, layWT + 0 * 262144, A1, 500, layers_b + 0 * 512, channels + 1 * 2048, nullptr);
    pers_k<1, 512><<<256, 512, 155648, stream>>>(A1, layWT + 1 * 262144, A0, 500, layers_b + 1 * 512, channels + 2 * 2048, nullptr);
    pers_k<2, 512><<<256, 512, 155648, stream>>>(A0, layWT + 2 * 262144, A1, 500, layers_b + 2 * 512, channels + 3 * 2048, Rb);
    pers_k<1, 512><<<256, 512, 155648, stream>>>(A1, layWT + 3 * 262144, A0, 500, layers_b + 3 * 512, channels + 4 * 2048, nullptr);
    pers_k<1, 512><<<256, 512, 155648, stream>>>(A0, layWT + 4 * 262144, A1, 500, layers_b + 4 * 512, channels + 5 * 2048, nullptr);
    pers_k<3, 512><<<256, 512, 155648, stream>>>(A1, layWT + 5 * 262144, A0, 500, layers_b + 5 * 512, channels + 6 * 2048, nullptr);

    final_k<<<MROWS, 256, 0, stream>>>(A0, out_W, out_b, (float*)d_out);
}